// Round 3
// baseline (1248.872 us; speedup 1.0000x reference)
//
#include <hip/hip_runtime.h>
#include <hip/hip_bf16.h>

#define Nn 100
#define Bb 8
#define Hh 256
#define Ee 9900
#define RE 79200   // Bb*Ee
#define RN 800     // Bb*Nn
#define BN_EPS 1e-5f

typedef __attribute__((ext_vector_type(8))) unsigned short ushort8_t;
typedef __attribute__((ext_vector_type(4))) unsigned short ushort4_t;

__device__ __forceinline__ float bf2f(unsigned short u){
  return __uint_as_float(((unsigned)u) << 16);
}
__device__ __forceinline__ unsigned short f2bf(float f){
  unsigned u = __float_as_uint(f);
  return (unsigned short)((u + 0x7fffu + ((u >> 16) & 1u)) >> 16);
}

// BN affine from raw stats: a = g*rsqrt(var+eps), c = beta - mu*a
__device__ __forceinline__ void affine_prologue(const float* __restrict__ stats,
    float cnt, const float* __restrict__ g, const float* __restrict__ beta,
    float* a, float* c, int tid){
  if (tid < 256){
    float inv = 1.0f / cnt;
    float mu  = stats[tid] * inv;
    float var = fmaxf(stats[256 + tid] * inv - mu * mu, 0.f);
    float aa  = g[tid] * rsqrtf(var + BN_EPS);
    a[tid] = aa;
    c[tid] = beta[tid] - mu * aa;
  }
}

// acc[8][4] += IN(32x256 f32 LDS) @ W(256x256 f32 global). thread: tr=tid>>6, tc=tid&63
__device__ __forceinline__ void gemm_f32(const float* IN, const float* __restrict__ W,
                                         float acc[8][4], int tr, int tc){
  for (int k = 0; k < 256; k += 4){
    float4 w0 = *(const float4*)(W + (size_t)(k+0)*256 + 4*tc);
    float4 w1 = *(const float4*)(W + (size_t)(k+1)*256 + 4*tc);
    float4 w2 = *(const float4*)(W + (size_t)(k+2)*256 + 4*tc);
    float4 w3 = *(const float4*)(W + (size_t)(k+3)*256 + 4*tc);
    #pragma unroll
    for (int rr = 0; rr < 8; rr++){
      float4 iv = *(const float4*)(IN + (tr*8+rr)*256 + k);
      acc[rr][0] += iv.x*w0.x + iv.y*w1.x + iv.z*w2.x + iv.w*w3.x;
      acc[rr][1] += iv.x*w0.y + iv.y*w1.y + iv.z*w2.y + iv.w*w3.y;
      acc[rr][2] += iv.x*w0.z + iv.y*w1.z + iv.z*w2.z + iv.w*w3.z;
      acc[rr][3] += iv.x*w0.w + iv.y*w1.w + iv.z*w2.w + iv.w*w3.w;
    }
  }
}

// acc[8][4] += IN(32xKW bf16 LDS) @ W(KWx256 f32 global)
template<int KW>
__device__ __forceinline__ void gemm_bf16(const unsigned short* IN, const float* __restrict__ W,
                                          float acc[8][4], int tr, int tc){
  for (int k = 0; k < KW; k += 8){
    float4 w[8];
    #pragma unroll
    for (int kk = 0; kk < 8; kk++)
      w[kk] = *(const float4*)(W + (size_t)(k+kk)*256 + 4*tc);
    #pragma unroll
    for (int rr = 0; rr < 8; rr++){
      ushort8_t iv = *(const ushort8_t*)(IN + (tr*8+rr)*KW + k);
      float f[8];
      #pragma unroll
      for (int kk = 0; kk < 8; kk++) f[kk] = bf2f(iv[kk]);
      #pragma unroll
      for (int kk = 0; kk < 8; kk++){
        acc[rr][0] += f[kk]*w[kk].x;
        acc[rr][1] += f[kk]*w[kk].y;
        acc[rr][2] += f[kk]*w[kk].z;
        acc[rr][3] += f[kk]*w[kk].w;
      }
    }
  }
}

// stats push helper: red[512] LDS partials -> global stats (256 threads: 2 entries each)
#define STATS_PUSH(statsp)                                   \
  __syncthreads();                                           \
  atomicAdd(&(statsp)[tid], red[tid]);                       \
  atomicAdd(&(statsp)[tid + 256], red[tid + 256]);

// ---------------- mlp1: [800,256] -> h1 (f32) + stats ----------------
__global__ __launch_bounds__(256,2) void k_mlp1(
    const float* __restrict__ x,
    const float* __restrict__ W1, const float* __restrict__ b1,
    const float* __restrict__ W2, const float* __restrict__ b2,
    float* __restrict__ h1, float* __restrict__ stats){
  __shared__ float IN[32*256];
  __shared__ float O1[32*256];
  __shared__ float red[512];
  int tid = threadIdx.x, tr = tid >> 6, tc = tid & 63;
  int r0 = blockIdx.x * 32;
  #pragma unroll
  for (int j = 0; j < 8; j++){
    int idx = tid*4 + j*1024;
    *(float4*)(IN + idx) = *(const float4*)(x + (size_t)r0*256 + idx);
  }
  red[tid] = 0.f; red[tid + 256] = 0.f;   // FIX: blockDim=256, cover all 512
  __syncthreads();
  float acc[8][4];
  #pragma unroll
  for (int rr = 0; rr < 8; rr++){ acc[rr][0]=acc[rr][1]=acc[rr][2]=acc[rr][3]=0.f; }
  gemm_f32(IN, W1, acc, tr, tc);
  {
    float4 bb = *(const float4*)(b1 + 4*tc);
    #pragma unroll
    for (int rr = 0; rr < 8; rr++){
      float4 o;
      o.x = fmaxf(acc[rr][0]+bb.x, 0.f);
      o.y = fmaxf(acc[rr][1]+bb.y, 0.f);
      o.z = fmaxf(acc[rr][2]+bb.z, 0.f);
      o.w = fmaxf(acc[rr][3]+bb.w, 0.f);
      *(float4*)(O1 + (tr*8+rr)*256 + 4*tc) = o;
    }
  }
  __syncthreads();
  #pragma unroll
  for (int rr = 0; rr < 8; rr++){ acc[rr][0]=acc[rr][1]=acc[rr][2]=acc[rr][3]=0.f; }
  gemm_f32(O1, W2, acc, tr, tc);
  {
    float4 bb = *(const float4*)(b2 + 4*tc);
    float ls0=0,ls1=0,ls2=0,ls3=0,lq0=0,lq1=0,lq2=0,lq3=0;
    #pragma unroll
    for (int rr = 0; rr < 8; rr++){
      float4 v;
      v.x = fmaxf(acc[rr][0]+bb.x, 0.f);
      v.y = fmaxf(acc[rr][1]+bb.y, 0.f);
      v.z = fmaxf(acc[rr][2]+bb.z, 0.f);
      v.w = fmaxf(acc[rr][3]+bb.w, 0.f);
      *(float4*)(h1 + ((size_t)(r0 + tr*8 + rr))*256 + 4*tc) = v;
      ls0+=v.x; lq0+=v.x*v.x; ls1+=v.y; lq1+=v.y*v.y;
      ls2+=v.z; lq2+=v.z*v.z; ls3+=v.w; lq3+=v.w*v.w;
    }
    atomicAdd(&red[4*tc+0], ls0); atomicAdd(&red[4*tc+1], ls1);
    atomicAdd(&red[4*tc+2], ls2); atomicAdd(&red[4*tc+3], ls3);
    atomicAdd(&red[256+4*tc+0], lq0); atomicAdd(&red[256+4*tc+1], lq1);
    atomicAdd(&red[256+4*tc+2], lq2); atomicAdd(&red[256+4*tc+3], lq3);
  }
  STATS_PUSH(stats)
}

// ---------------- mlp2: gather(h1)+bn1 -> [79200,512] -> h2 (bf16) + stats ----------------
__global__ __launch_bounds__(256,2) void k_mlp2(
    const float* __restrict__ h1, const float* __restrict__ stats1,
    const float* __restrict__ g1, const float* __restrict__ be1,
    const float* __restrict__ W1, const float* __restrict__ b1,
    const float* __restrict__ W2, const float* __restrict__ b2,
    unsigned short* __restrict__ h2, float* __restrict__ stats2){
  __shared__ unsigned short A[32*512];
  __shared__ unsigned short O1[32*256];
  __shared__ float ap[256], cp[256];
  __shared__ float red[512];
  int tid = threadIdx.x, tr = tid >> 6, lane = tid & 63, tc = lane;
  int r0 = blockIdx.x * 32;
  affine_prologue(stats1, (float)RN, g1, be1, ap, cp, tid);
  red[tid] = 0.f; red[tid + 256] = 0.f;   // FIX
  __syncthreads();
  {
    int cb = (lane & 31) * 8, half = lane >> 5;
    float4 a0 = *(const float4*)(ap+cb), a1 = *(const float4*)(ap+cb+4);
    float4 c0 = *(const float4*)(cp+cb), c1 = *(const float4*)(cp+cb+4);
    #pragma unroll
    for (int rr = 0; rr < 8; rr++){
      int rl = tr*8+rr, rg = r0 + rl;
      int b = rg / Ee, e = rg - b*Ee;
      int i = e / 99, kk = e - i*99;
      int snd = kk + (kk >= i);
      int node = half ? i : snd;
      const float* sp = h1 + ((size_t)(b*Nn + node))*256 + cb;
      float4 v0 = *(const float4*)sp, v1 = *(const float4*)(sp+4);
      ushort8_t o;
      o[0]=f2bf(v0.x*a0.x+c0.x); o[1]=f2bf(v0.y*a0.y+c0.y);
      o[2]=f2bf(v0.z*a0.z+c0.z); o[3]=f2bf(v0.w*a0.w+c0.w);
      o[4]=f2bf(v1.x*a1.x+c1.x); o[5]=f2bf(v1.y*a1.y+c1.y);
      o[6]=f2bf(v1.z*a1.z+c1.z); o[7]=f2bf(v1.w*a1.w+c1.w);
      *(ushort8_t*)(A + rl*512 + half*256 + cb) = o;
    }
  }
  __syncthreads();
  float acc[8][4];
  #pragma unroll
  for (int rr = 0; rr < 8; rr++){ acc[rr][0]=acc[rr][1]=acc[rr][2]=acc[rr][3]=0.f; }
  gemm_bf16<512>(A, W1, acc, tr, tc);
  {
    float4 bb = *(const float4*)(b1 + 4*tc);
    #pragma unroll
    for (int rr = 0; rr < 8; rr++){
      ushort4_t o;
      o[0]=f2bf(fmaxf(acc[rr][0]+bb.x,0.f));
      o[1]=f2bf(fmaxf(acc[rr][1]+bb.y,0.f));
      o[2]=f2bf(fmaxf(acc[rr][2]+bb.z,0.f));
      o[3]=f2bf(fmaxf(acc[rr][3]+bb.w,0.f));
      *(ushort4_t*)(O1 + (tr*8+rr)*256 + 4*tc) = o;
    }
  }
  __syncthreads();
  #pragma unroll
  for (int rr = 0; rr < 8; rr++){ acc[rr][0]=acc[rr][1]=acc[rr][2]=acc[rr][3]=0.f; }
  gemm_bf16<256>(O1, W2, acc, tr, tc);
  {
    float4 bb = *(const float4*)(b2 + 4*tc);
    float ls0=0,ls1=0,ls2=0,ls3=0,lq0=0,lq1=0,lq2=0,lq3=0;
    #pragma unroll
    for (int rr = 0; rr < 8; rr++){
      float v0 = fmaxf(acc[rr][0]+bb.x, 0.f);
      float v1 = fmaxf(acc[rr][1]+bb.y, 0.f);
      float v2 = fmaxf(acc[rr][2]+bb.z, 0.f);
      float v3 = fmaxf(acc[rr][3]+bb.w, 0.f);
      ushort4_t o; o[0]=f2bf(v0); o[1]=f2bf(v1); o[2]=f2bf(v2); o[3]=f2bf(v3);
      *(ushort4_t*)(h2 + ((size_t)(r0 + tr*8 + rr))*256 + 4*tc) = o;
      ls0+=v0; lq0+=v0*v0; ls1+=v1; lq1+=v1*v1;
      ls2+=v2; lq2+=v2*v2; ls3+=v3; lq3+=v3*v3;
    }
    atomicAdd(&red[4*tc+0], ls0); atomicAdd(&red[4*tc+1], ls1);
    atomicAdd(&red[4*tc+2], ls2); atomicAdd(&red[4*tc+3], ls3);
    atomicAdd(&red[256+4*tc+0], lq0); atomicAdd(&red[256+4*tc+1], lq1);
    atomicAdd(&red[256+4*tc+2], lq2); atomicAdd(&red[256+4*tc+3], lq3);
  }
  STATS_PUSH(stats2)
}

// ---------------- mlp3: edge2node(bn2(h2)) -> [800,256] -> h3 (f32) + stats ----------------
__global__ __launch_bounds__(256,2) void k_mlp3(
    const unsigned short* __restrict__ h2, const float* __restrict__ stats2,
    const float* __restrict__ g2, const float* __restrict__ be2,
    const float* __restrict__ W1, const float* __restrict__ b1,
    const float* __restrict__ W2, const float* __restrict__ b2,
    float* __restrict__ h3, float* __restrict__ stats3){
  __shared__ float IN[32*256];
  __shared__ float O1[32*256];
  __shared__ float red[512];
  __shared__ float ap[256], cp[256];
  int tid = threadIdx.x, tr = tid >> 6, lane = tid & 63, tc = lane;
  int r0 = blockIdx.x * 32;
  affine_prologue(stats2, (float)RE, g2, be2, ap, cp, tid);
  red[tid] = 0.f; red[tid + 256] = 0.f;   // FIX
  __syncthreads();
  {
    int cb = lane * 4;
    float4 av = *(const float4*)(ap+cb), cv = *(const float4*)(cp+cb);
    #pragma unroll
    for (int rr = 0; rr < 8; rr++){
      int m = r0 + tr*8 + rr;          // node-row 0..799
      int b = m / Nn, i = m - b*Nn;
      const unsigned short* base = h2 + ((size_t)(b*Ee + i*99))*256 + cb;
      float s0=0,s1=0,s2=0,s3=0;
      for (int j = 0; j < 99; j++){
        ushort4_t hv = *(const ushort4_t*)(base + (size_t)j*256);
        s0 += bf2f(hv[0]); s1 += bf2f(hv[1]);
        s2 += bf2f(hv[2]); s3 += bf2f(hv[3]);
      }
      float4 o;
      o.x = (s0*av.x + 99.f*cv.x) * 0.01f;
      o.y = (s1*av.y + 99.f*cv.y) * 0.01f;
      o.z = (s2*av.z + 99.f*cv.z) * 0.01f;
      o.w = (s3*av.w + 99.f*cv.w) * 0.01f;
      *(float4*)(IN + (tr*8+rr)*256 + cb) = o;
    }
  }
  __syncthreads();
  float acc[8][4];
  #pragma unroll
  for (int rr = 0; rr < 8; rr++){ acc[rr][0]=acc[rr][1]=acc[rr][2]=acc[rr][3]=0.f; }
  gemm_f32(IN, W1, acc, tr, tc);
  {
    float4 bb = *(const float4*)(b1 + 4*tc);
    #pragma unroll
    for (int rr = 0; rr < 8; rr++){
      float4 o;
      o.x = fmaxf(acc[rr][0]+bb.x, 0.f);
      o.y = fmaxf(acc[rr][1]+bb.y, 0.f);
      o.z = fmaxf(acc[rr][2]+bb.z, 0.f);
      o.w = fmaxf(acc[rr][3]+bb.w, 0.f);
      *(float4*)(O1 + (tr*8+rr)*256 + 4*tc) = o;
    }
  }
  __syncthreads();
  #pragma unroll
  for (int rr = 0; rr < 8; rr++){ acc[rr][0]=acc[rr][1]=acc[rr][2]=acc[rr][3]=0.f; }
  gemm_f32(O1, W2, acc, tr, tc);
  {
    float4 bb = *(const float4*)(b2 + 4*tc);
    float ls0=0,ls1=0,ls2=0,ls3=0,lq0=0,lq1=0,lq2=0,lq3=0;
    #pragma unroll
    for (int rr = 0; rr < 8; rr++){
      float4 v;
      v.x = fmaxf(acc[rr][0]+bb.x, 0.f);
      v.y = fmaxf(acc[rr][1]+bb.y, 0.f);
      v.z = fmaxf(acc[rr][2]+bb.z, 0.f);
      v.w = fmaxf(acc[rr][3]+bb.w, 0.f);
      *(float4*)(h3 + ((size_t)(r0 + tr*8 + rr))*256 + 4*tc) = v;
      ls0+=v.x; lq0+=v.x*v.x; ls1+=v.y; lq1+=v.y*v.y;
      ls2+=v.z; lq2+=v.z*v.z; ls3+=v.w; lq3+=v.w*v.w;
    }
    atomicAdd(&red[4*tc+0], ls0); atomicAdd(&red[4*tc+1], ls1);
    atomicAdd(&red[4*tc+2], ls2); atomicAdd(&red[4*tc+3], ls3);
    atomicAdd(&red[256+4*tc+0], lq0); atomicAdd(&red[256+4*tc+1], lq1);
    atomicAdd(&red[256+4*tc+2], lq2); atomicAdd(&red[256+4*tc+3], lq3);
  }
  STATS_PUSH(stats3)
}

// ---------------- mlp4: [gather(bn3(h3)), bn2(h2)] -> [79200,768] -> h4 (bf16) + stats ----------------
__global__ __launch_bounds__(256,2) void k_mlp4(
    const float* __restrict__ h3, const unsigned short* __restrict__ h2,
    const float* __restrict__ stats3, const float* __restrict__ g3, const float* __restrict__ be3,
    const float* __restrict__ stats2, const float* __restrict__ g2, const float* __restrict__ be2,
    const float* __restrict__ W1, const float* __restrict__ b1,
    const float* __restrict__ W2, const float* __restrict__ b2,
    unsigned short* __restrict__ h4, float* __restrict__ stats4){
  __shared__ unsigned short A[32*768];
  __shared__ unsigned short O1[32*256];
  __shared__ float a3[256], c3[256], a2[256], c2[256];
  __shared__ float red[512];
  int tid = threadIdx.x, tr = tid >> 6, lane = tid & 63, tc = lane;
  int r0 = blockIdx.x * 32;
  affine_prologue(stats3, (float)RN, g3, be3, a3, c3, tid);
  affine_prologue(stats2, (float)RE, g2, be2, a2, c2, tid);
  red[tid] = 0.f; red[tid + 256] = 0.f;   // FIX
  __syncthreads();
  {
    // part A: cols 0..511 from h3 (bn3), senders then receivers
    int cb = (lane & 31) * 8, half = lane >> 5;
    float4 a0 = *(const float4*)(a3+cb), a1 = *(const float4*)(a3+cb+4);
    float4 c0 = *(const float4*)(c3+cb), c1 = *(const float4*)(c3+cb+4);
    #pragma unroll
    for (int rr = 0; rr < 8; rr++){
      int rl = tr*8+rr, rg = r0 + rl;
      int b = rg / Ee, e = rg - b*Ee;
      int i = e / 99, kk = e - i*99;
      int snd = kk + (kk >= i);
      int node = half ? i : snd;
      const float* sp = h3 + ((size_t)(b*Nn + node))*256 + cb;
      float4 v0 = *(const float4*)sp, v1 = *(const float4*)(sp+4);
      ushort8_t o;
      o[0]=f2bf(v0.x*a0.x+c0.x); o[1]=f2bf(v0.y*a0.y+c0.y);
      o[2]=f2bf(v0.z*a0.z+c0.z); o[3]=f2bf(v0.w*a0.w+c0.w);
      o[4]=f2bf(v1.x*a1.x+c1.x); o[5]=f2bf(v1.y*a1.y+c1.y);
      o[6]=f2bf(v1.z*a1.z+c1.z); o[7]=f2bf(v1.w*a1.w+c1.w);
      *(ushort8_t*)(A + rl*768 + half*256 + cb) = o;
    }
  }
  {
    // part B: cols 512..767 = bn2(h2[row]) (the skip connection)
    int cb = lane * 4;
    float4 av = *(const float4*)(a2+cb), cv = *(const float4*)(c2+cb);
    #pragma unroll
    for (int rr = 0; rr < 8; rr++){
      int rl = tr*8+rr, rg = r0 + rl;
      ushort4_t hv = *(const ushort4_t*)(h2 + (size_t)rg*256 + cb);
      ushort4_t o;
      o[0]=f2bf(bf2f(hv[0])*av.x+cv.x);
      o[1]=f2bf(bf2f(hv[1])*av.y+cv.y);
      o[2]=f2bf(bf2f(hv[2])*av.z+cv.z);
      o[3]=f2bf(bf2f(hv[3])*av.w+cv.w);
      *(ushort4_t*)(A + rl*768 + 512 + cb) = o;
    }
  }
  __syncthreads();
  float acc[8][4];
  #pragma unroll
  for (int rr = 0; rr < 8; rr++){ acc[rr][0]=acc[rr][1]=acc[rr][2]=acc[rr][3]=0.f; }
  gemm_bf16<768>(A, W1, acc, tr, tc);
  {
    float4 bb = *(const float4*)(b1 + 4*tc);
    #pragma unroll
    for (int rr = 0; rr < 8; rr++){
      ushort4_t o;
      o[0]=f2bf(fmaxf(acc[rr][0]+bb.x,0.f));
      o[1]=f2bf(fmaxf(acc[rr][1]+bb.y,0.f));
      o[2]=f2bf(fmaxf(acc[rr][2]+bb.z,0.f));
      o[3]=f2bf(fmaxf(acc[rr][3]+bb.w,0.f));
      *(ushort4_t*)(O1 + (tr*8+rr)*256 + 4*tc) = o;
    }
  }
  __syncthreads();
  #pragma unroll
  for (int rr = 0; rr < 8; rr++){ acc[rr][0]=acc[rr][1]=acc[rr][2]=acc[rr][3]=0.f; }
  gemm_bf16<256>(O1, W2, acc, tr, tc);
  {
    float4 bb = *(const float4*)(b2 + 4*tc);
    float ls0=0,ls1=0,ls2=0,ls3=0,lq0=0,lq1=0,lq2=0,lq3=0;
    #pragma unroll
    for (int rr = 0; rr < 8; rr++){
      float v0 = fmaxf(acc[rr][0]+bb.x, 0.f);
      float v1 = fmaxf(acc[rr][1]+bb.y, 0.f);
      float v2 = fmaxf(acc[rr][2]+bb.z, 0.f);
      float v3 = fmaxf(acc[rr][3]+bb.w, 0.f);
      ushort4_t o; o[0]=f2bf(v0); o[1]=f2bf(v1); o[2]=f2bf(v2); o[3]=f2bf(v3);
      *(ushort4_t*)(h4 + ((size_t)(r0 + tr*8 + rr))*256 + 4*tc) = o;
      ls0+=v0; lq0+=v0*v0; ls1+=v1; lq1+=v1*v1;
      ls2+=v2; lq2+=v2*v2; ls3+=v3; lq3+=v3*v3;
    }
    atomicAdd(&red[4*tc+0], ls0); atomicAdd(&red[4*tc+1], ls1);
    atomicAdd(&red[4*tc+2], ls2); atomicAdd(&red[4*tc+3], ls3);
    atomicAdd(&red[256+4*tc+0], lq0); atomicAdd(&red[256+4*tc+1], lq1);
    atomicAdd(&red[256+4*tc+2], lq2); atomicAdd(&red[256+4*tc+3], lq3);
  }
  STATS_PUSH(stats4)
}

// ---------------- out: bn4(h4) @ fc_w + fc_b -> [79200,4] f32 ----------------
__global__ __launch_bounds__(256,2) void k_out(
    const unsigned short* __restrict__ h4, const float* __restrict__ stats4,
    const float* __restrict__ g4, const float* __restrict__ be4,
    const float* __restrict__ fcw, const float* __restrict__ fcb,
    float* __restrict__ out){
  __shared__ unsigned short T[64*264];   // pad 256->264 to break bank alignment
  __shared__ float a4[256], c4[256], Wl[1024];
  int tid = threadIdx.x;
  affine_prologue(stats4, (float)RE, g4, be4, a4, c4, tid);
  #pragma unroll
  for (int j = 0; j < 4; j++){ int id = tid + j*256; Wl[id] = fcw[id]; }
  int r0 = blockIdx.x * 64;
  #pragma unroll
  for (int j = 0; j < 8; j++){
    int flat = tid + j*256;            // 2048 ushort8 chunks = 64 rows x 32 chunks
    int rl = flat >> 5, cs = (flat & 31) * 8;
    ushort8_t v = {0,0,0,0,0,0,0,0};
    if (r0 + rl < RE) v = *(const ushort8_t*)(h4 + (size_t)(r0+rl)*256 + cs);
    *(ushort8_t*)(&T[rl*264 + cs]) = v;
  }
  __syncthreads();
  int row = tid >> 2, o = tid & 3;
  if (r0 + row < RE){
    float acc = fcb[o];
    for (int k = 0; k < 256; k += 8){
      ushort8_t iv = *(const ushort8_t*)(&T[row*264 + k]);
      #pragma unroll
      for (int kk = 0; kk < 8; kk++){
        float v = bf2f(iv[kk]) * a4[k+kk] + c4[k+kk];
        acc += v * Wl[(k+kk)*4 + o];
      }
    }
    out[(size_t)(r0+row)*4 + o] = acc;
  }
}

extern "C" void kernel_launch(void* const* d_in, const int* in_sizes, int n_in,
                              void* d_out, int out_size, void* d_ws, size_t ws_size,
                              hipStream_t stream){
  const float* x    = (const float*)d_in[0];
  const float* m1w1 = (const float*)d_in[6];  const float* m1b1 = (const float*)d_in[7];
  const float* m1w2 = (const float*)d_in[8];  const float* m1b2 = (const float*)d_in[9];
  const float* m1g  = (const float*)d_in[10]; const float* m1be = (const float*)d_in[11];
  const float* m2w1 = (const float*)d_in[12]; const float* m2b1 = (const float*)d_in[13];
  const float* m2w2 = (const float*)d_in[14]; const float* m2b2 = (const float*)d_in[15];
  const float* m2g  = (const float*)d_in[16]; const float* m2be = (const float*)d_in[17];
  const float* m3w1 = (const float*)d_in[18]; const float* m3b1 = (const float*)d_in[19];
  const float* m3w2 = (const float*)d_in[20]; const float* m3b2 = (const float*)d_in[21];
  const float* m3g  = (const float*)d_in[22]; const float* m3be = (const float*)d_in[23];
  const float* m4w1 = (const float*)d_in[24]; const float* m4b1 = (const float*)d_in[25];
  const float* m4w2 = (const float*)d_in[26]; const float* m4b2 = (const float*)d_in[27];
  const float* m4g  = (const float*)d_in[28]; const float* m4be = (const float*)d_in[29];
  const float* fcw  = (const float*)d_in[30]; const float* fcb  = (const float*)d_in[31];

  // Workspace layout (floats): h1[204800] h3[204800] stats[2048] then bf16 h2,h4
  size_t need_bytes = (204800ull + 204800ull + 2048ull) * 4ull
                    + 2ull * (size_t)RE * 256ull * 2ull;   // ~79 MB
  if (ws_size < need_bytes) return;   // diagnosable clean failure instead of OOB crash

  float* ws = (float*)d_ws;
  float* h1 = ws;                        // 800*256 f32
  float* h3 = ws + 204800;               // 800*256 f32
  float* stats = ws + 409600;            // 4 stages x 512 f32 (sum|sumsq)
  unsigned short* h2 = (unsigned short*)(stats + 2048);   // 79200*256 bf16
  unsigned short* h4 = h2 + (size_t)RE * 256;             // 79200*256 bf16

  hipMemsetAsync(stats, 0, 2048 * sizeof(float), stream);

  k_mlp1<<<RN/32, 256, 0, stream>>>(x, m1w1, m1b1, m1w2, m1b2, h1, stats);
  k_mlp2<<<RE/32, 256, 0, stream>>>(h1, stats, m1g, m1be,
                                    m2w1, m2b1, m2w2, m2b2, h2, stats + 512);
  k_mlp3<<<RN/32, 256, 0, stream>>>(h2, stats + 512, m2g, m2be,
                                    m3w1, m3b1, m3w2, m3b2, h3, stats + 1024);
  k_mlp4<<<RE/32, 256, 0, stream>>>(h3, h2, stats + 1024, m3g, m3be,
                                    stats + 512, m2g, m2be,
                                    m4w1, m4b1, m4w2, m4b2, h4, stats + 1536);
  k_out<<<(RE+63)/64, 256, 0, stream>>>(h4, stats + 1536, m4g, m4be,
                                        fcw, fcb, (float*)d_out);
}

// Round 5
// 498.192 us; speedup vs baseline: 2.5068x; 2.5068x over previous
//
#include <hip/hip_runtime.h>
#include <hip/hip_bf16.h>

#define Nn 100
#define Bb 8
#define Hh 256
#define Ee 9900
#define RE 79200   // Bb*Ee
#define RN 800     // Bb*Nn
#define BN_EPS 1e-5f

typedef __attribute__((ext_vector_type(8))) unsigned short ushort8_t;
typedef __attribute__((ext_vector_type(4))) unsigned short ushort4_t;
typedef __attribute__((ext_vector_type(8))) short bf16x8;   // MFMA A/B frag (4 VGPRs)
typedef __attribute__((ext_vector_type(4))) float f32x4;    // MFMA C/D frag

__device__ __forceinline__ float bf2f(unsigned short u){
  return __uint_as_float(((unsigned)u) << 16);
}
__device__ __forceinline__ unsigned short f2bf(float f){
  unsigned u = __float_as_uint(f);
  return (unsigned short)((u + 0x7fffu + ((u >> 16) & 1u)) >> 16);
}

// BN affine from raw stats: a = g*rsqrt(var+eps), c = beta - mu*a
__device__ __forceinline__ void affine_prologue(const float* __restrict__ stats,
    float cnt, const float* __restrict__ g, const float* __restrict__ beta,
    float* a, float* c, int tid){
  if (tid < 256){
    float inv = 1.0f / cnt;
    float mu  = stats[tid] * inv;
    float var = fmaxf(stats[256 + tid] * inv - mu * mu, 0.f);
    float aa  = g[tid] * rsqrtf(var + BN_EPS);
    a[tid] = aa;
    c[tid] = beta[tid] - mu * aa;
  }
}

// acc[8][4] += IN(32x256 f32 LDS) @ W(256x256 f32 global). thread: tr=tid>>6, tc=tid&63
__device__ __forceinline__ void gemm_f32(const float* IN, const float* __restrict__ W,
                                         float acc[8][4], int tr, int tc){
  for (int k = 0; k < 256; k += 4){
    float4 w0 = *(const float4*)(W + (size_t)(k+0)*256 + 4*tc);
    float4 w1 = *(const float4*)(W + (size_t)(k+1)*256 + 4*tc);
    float4 w2 = *(const float4*)(W + (size_t)(k+2)*256 + 4*tc);
    float4 w3 = *(const float4*)(W + (size_t)(k+3)*256 + 4*tc);
    #pragma unroll
    for (int rr = 0; rr < 8; rr++){
      float4 iv = *(const float4*)(IN + (tr*8+rr)*256 + k);
      acc[rr][0] += iv.x*w0.x + iv.y*w1.x + iv.z*w2.x + iv.w*w3.x;
      acc[rr][1] += iv.x*w0.y + iv.y*w1.y + iv.z*w2.y + iv.w*w3.y;
      acc[rr][2] += iv.x*w0.z + iv.y*w1.z + iv.z*w2.z + iv.w*w3.z;
      acc[rr][3] += iv.x*w0.w + iv.y*w1.w + iv.z*w2.w + iv.w*w3.w;
    }
  }
}

// MFMA GEMM: A = LDS [32][KW] bf16 row-major, XOR-swizzled (byte ^= (row&7)<<4).
// B = fragment-packed bf16 weights (see k_wprep). Wave w owns output cols [w*64, w*64+64).
template<int KW>
__device__ __forceinline__ void mfma_gemm(const unsigned short* Alds,
    const unsigned short* __restrict__ Bf, f32x4 acc[2][4], int w, int lane){
  const int l15 = lane & 15, kg = lane >> 4;
  for (int ks = 0; ks < KW/32; ks++){
    int byte0 = ((l15*KW      + ks*32 + kg*8) * 2) ^ ((l15 & 7) << 4);
    int byte1 = (((16+l15)*KW + ks*32 + kg*8) * 2) ^ ((l15 & 7) << 4);
    bf16x8 a0 = *(const bf16x8*)((const char*)Alds + byte0);
    bf16x8 a1 = *(const bf16x8*)((const char*)Alds + byte1);
    const unsigned short* bp = Bf + ((size_t)(ks*16 + w*4)*64 + lane)*8;
    #pragma unroll
    for (int cf = 0; cf < 4; cf++){
      bf16x8 b = *(const bf16x8*)(bp + cf*64*8);
      acc[0][cf] = __builtin_amdgcn_mfma_f32_16x16x32_bf16(a0, b, acc[0][cf], 0,0,0);
      acc[1][cf] = __builtin_amdgcn_mfma_f32_16x16x32_bf16(a1, b, acc[1][cf], 0,0,0);
    }
  }
}

__device__ __forceinline__ void zero_acc(f32x4 acc[2][4]){
  #pragma unroll
  for (int i = 0; i < 2; i++)
    #pragma unroll
    for (int j = 0; j < 4; j++){
      f32x4 z = {0.f, 0.f, 0.f, 0.f};
      acc[i][j] = z;
    }
}

// stats push helper: red[512] LDS partials -> global stats (256 threads: 2 entries each)
#define STATS_PUSH(statsp)                                   \
  __syncthreads();                                           \
  atomicAdd(&(statsp)[tid], red[tid]);                       \
  atomicAdd(&(statsp)[tid + 256], red[tid + 256]);

// ---------------- weight prep: W f32 [ktiles*32, 256] -> B-fragment bf16 layout ----------------
// out[((tk*16+tc)*64 + lane)*8 + j] = bf16( W[tk*32 + (lane>>4)*8 + j][tc*16 + (lane&15)] )
__global__ void k_wprep(const float* __restrict__ W, unsigned short* __restrict__ out,
                        int ktiles){
  int id = blockIdx.x * 256 + threadIdx.x;
  int total = ktiles * 16 * 64;
  if (id >= total) return;
  int lane = id & 63, tile = id >> 6;
  int tc = tile & 15, tk = tile >> 4;
  int kbase = tk*32 + (lane>>4)*8, col = tc*16 + (lane&15);
  ushort8_t o;
  #pragma unroll
  for (int j = 0; j < 8; j++) o[j] = f2bf(W[(size_t)(kbase+j)*256 + col]);
  *(ushort8_t*)(out + (size_t)id*8) = o;
}

// ---------------- mlp1: [800,256] -> h1 (f32) + stats (f32 VALU; small) ----------------
__global__ __launch_bounds__(256,2) void k_mlp1(
    const float* __restrict__ x,
    const float* __restrict__ W1, const float* __restrict__ b1,
    const float* __restrict__ W2, const float* __restrict__ b2,
    float* __restrict__ h1, float* __restrict__ stats){
  __shared__ float IN[32*256];
  __shared__ float O1[32*256];
  __shared__ float red[512];
  int tid = threadIdx.x, tr = tid >> 6, tc = tid & 63;
  int r0 = blockIdx.x * 32;
  #pragma unroll
  for (int j = 0; j < 8; j++){
    int idx = tid*4 + j*1024;
    *(float4*)(IN + idx) = *(const float4*)(x + (size_t)r0*256 + idx);
  }
  red[tid] = 0.f; red[tid + 256] = 0.f;
  __syncthreads();
  float acc[8][4];
  #pragma unroll
  for (int rr = 0; rr < 8; rr++){ acc[rr][0]=acc[rr][1]=acc[rr][2]=acc[rr][3]=0.f; }
  gemm_f32(IN, W1, acc, tr, tc);
  {
    float4 bb = *(const float4*)(b1 + 4*tc);
    #pragma unroll
    for (int rr = 0; rr < 8; rr++){
      float4 o;
      o.x = fmaxf(acc[rr][0]+bb.x, 0.f);
      o.y = fmaxf(acc[rr][1]+bb.y, 0.f);
      o.z = fmaxf(acc[rr][2]+bb.z, 0.f);
      o.w = fmaxf(acc[rr][3]+bb.w, 0.f);
      *(float4*)(O1 + (tr*8+rr)*256 + 4*tc) = o;
    }
  }
  __syncthreads();
  #pragma unroll
  for (int rr = 0; rr < 8; rr++){ acc[rr][0]=acc[rr][1]=acc[rr][2]=acc[rr][3]=0.f; }
  gemm_f32(O1, W2, acc, tr, tc);
  {
    float4 bb = *(const float4*)(b2 + 4*tc);
    float ls0=0,ls1=0,ls2=0,ls3=0,lq0=0,lq1=0,lq2=0,lq3=0;
    #pragma unroll
    for (int rr = 0; rr < 8; rr++){
      float4 v;
      v.x = fmaxf(acc[rr][0]+bb.x, 0.f);
      v.y = fmaxf(acc[rr][1]+bb.y, 0.f);
      v.z = fmaxf(acc[rr][2]+bb.z, 0.f);
      v.w = fmaxf(acc[rr][3]+bb.w, 0.f);
      *(float4*)(h1 + ((size_t)(r0 + tr*8 + rr))*256 + 4*tc) = v;
      ls0+=v.x; lq0+=v.x*v.x; ls1+=v.y; lq1+=v.y*v.y;
      ls2+=v.z; lq2+=v.z*v.z; ls3+=v.w; lq3+=v.w*v.w;
    }
    atomicAdd(&red[4*tc+0], ls0); atomicAdd(&red[4*tc+1], ls1);
    atomicAdd(&red[4*tc+2], ls2); atomicAdd(&red[4*tc+3], ls3);
    atomicAdd(&red[256+4*tc+0], lq0); atomicAdd(&red[256+4*tc+1], lq1);
    atomicAdd(&red[256+4*tc+2], lq2); atomicAdd(&red[256+4*tc+3], lq3);
  }
  STATS_PUSH(stats)
}

// ---------------- mlp2 (MFMA): gather(h1)+bn1 -> [79200,512] -> h2 (bf16) + stats ----------------
__global__ __launch_bounds__(256,2) void k_mlp2(
    const float* __restrict__ h1, const float* __restrict__ stats1,
    const float* __restrict__ g1, const float* __restrict__ be1,
    const unsigned short* __restrict__ W1f, const float* __restrict__ b1,
    const unsigned short* __restrict__ W2f, const float* __restrict__ b2,
    unsigned short* __restrict__ h2, float* __restrict__ stats2){
  __shared__ unsigned short A[32*512];    // swizzled
  __shared__ unsigned short O1[32*256];   // swizzled
  __shared__ float ap[256], cp[256];
  __shared__ float red[512];
  int tid = threadIdx.x, w = tid >> 6, lane = tid & 63;
  int l15 = lane & 15, kg = lane >> 4;
  int r0 = blockIdx.x * 32;
  affine_prologue(stats1, (float)RN, g1, be1, ap, cp, tid);
  red[tid] = 0.f; red[tid + 256] = 0.f;
  __syncthreads();
  { // gather + bn1 -> A (swizzled bf16)
    int cb = (lane & 31) * 8, half = lane >> 5;
    float4 a0 = *(const float4*)(ap+cb), a1 = *(const float4*)(ap+cb+4);
    float4 c0 = *(const float4*)(cp+cb), c1 = *(const float4*)(cp+cb+4);
    #pragma unroll
    for (int rr = 0; rr < 8; rr++){
      int rl = w*8+rr, rg = r0 + rl;
      int b = rg / Ee, e = rg - b*Ee;
      int i = e / 99, kk = e - i*99;
      int snd = kk + (kk >= i);
      int node = half ? i : snd;
      const float* sp = h1 + ((size_t)(b*Nn + node))*256 + cb;
      float4 v0 = *(const float4*)sp, v1 = *(const float4*)(sp+4);
      ushort8_t o;
      o[0]=f2bf(v0.x*a0.x+c0.x); o[1]=f2bf(v0.y*a0.y+c0.y);
      o[2]=f2bf(v0.z*a0.z+c0.z); o[3]=f2bf(v0.w*a0.w+c0.w);
      o[4]=f2bf(v1.x*a1.x+c1.x); o[5]=f2bf(v1.y*a1.y+c1.y);
      o[6]=f2bf(v1.z*a1.z+c1.z); o[7]=f2bf(v1.w*a1.w+c1.w);
      int byte = ((rl*512 + half*256 + cb)*2) ^ ((rl&7)<<4);
      *(ushort8_t*)((char*)A + byte) = o;
    }
  }
  __syncthreads();
  f32x4 acc[2][4];
  zero_acc(acc);
  mfma_gemm<512>(A, W1f, acc, w, lane);
  { // bias+relu -> O1 (swizzled bf16)
    #pragma unroll
    for (int cf = 0; cf < 4; cf++){
      int col = w*64 + cf*16 + l15;
      float bb = b1[col];
      #pragma unroll
      for (int rf = 0; rf < 2; rf++){
        #pragma unroll
        for (int r = 0; r < 4; r++){
          int row = rf*16 + kg*4 + r;
          float v = fmaxf(acc[rf][cf][r] + bb, 0.f);
          int byte = ((row*256 + col)*2) ^ ((row&7)<<4);
          *(unsigned short*)((char*)O1 + byte) = f2bf(v);
        }
      }
    }
  }
  __syncthreads();
  f32x4 acc2[2][4];
  zero_acc(acc2);
  mfma_gemm<256>(O1, W2f, acc2, w, lane);
  { // bias+relu -> h2 + stats
    #pragma unroll
    for (int cf = 0; cf < 4; cf++){
      int col = w*64 + cf*16 + l15;
      float bb = b2[col];
      float ls = 0.f, lq = 0.f;
      #pragma unroll
      for (int rf = 0; rf < 2; rf++){
        #pragma unroll
        for (int r = 0; r < 4; r++){
          int row = rf*16 + kg*4 + r;
          float v = fmaxf(acc2[rf][cf][r] + bb, 0.f);
          h2[(size_t)(r0 + row)*256 + col] = f2bf(v);
          ls += v; lq += v*v;
        }
      }
      atomicAdd(&red[col], ls);
      atomicAdd(&red[256+col], lq);
    }
  }
  STATS_PUSH(stats2)
}

// ---------------- mlp3: edge2node(bn2(h2)) -> [800,256] -> h3 (f32) + stats ----------------
__global__ __launch_bounds__(256,2) void k_mlp3(
    const unsigned short* __restrict__ h2, const float* __restrict__ stats2,
    const float* __restrict__ g2, const float* __restrict__ be2,
    const float* __restrict__ W1, const float* __restrict__ b1,
    const float* __restrict__ W2, const float* __restrict__ b2,
    float* __restrict__ h3, float* __restrict__ stats3){
  __shared__ float IN[32*256];
  __shared__ float O1[32*256];
  __shared__ float red[512];
  __shared__ float ap[256], cp[256];
  int tid = threadIdx.x, tr = tid >> 6, lane = tid & 63, tc = lane;
  int r0 = blockIdx.x * 32;
  affine_prologue(stats2, (float)RE, g2, be2, ap, cp, tid);
  red[tid] = 0.f; red[tid + 256] = 0.f;
  __syncthreads();
  {
    int cb = lane * 4;
    float4 av = *(const float4*)(ap+cb), cv = *(const float4*)(cp+cb);
    #pragma unroll
    for (int rr = 0; rr < 8; rr++){
      int m = r0 + tr*8 + rr;          // node-row 0..799
      int b = m / Nn, i = m - b*Nn;
      const unsigned short* base = h2 + ((size_t)(b*Ee + i*99))*256 + cb;
      float s0=0,s1=0,s2=0,s3=0;
      for (int j = 0; j < 99; j++){
        ushort4_t hv = *(const ushort4_t*)(base + (size_t)j*256);
        s0 += bf2f(hv[0]); s1 += bf2f(hv[1]);
        s2 += bf2f(hv[2]); s3 += bf2f(hv[3]);
      }
      float4 o;
      o.x = (s0*av.x + 99.f*cv.x) * 0.01f;
      o.y = (s1*av.y + 99.f*cv.y) * 0.01f;
      o.z = (s2*av.z + 99.f*cv.z) * 0.01f;
      o.w = (s3*av.w + 99.f*cv.w) * 0.01f;
      *(float4*)(IN + (tr*8+rr)*256 + cb) = o;
    }
  }
  __syncthreads();
  float acc[8][4];
  #pragma unroll
  for (int rr = 0; rr < 8; rr++){ acc[rr][0]=acc[rr][1]=acc[rr][2]=acc[rr][3]=0.f; }
  gemm_f32(IN, W1, acc, tr, tc);
  {
    float4 bb = *(const float4*)(b1 + 4*tc);
    #pragma unroll
    for (int rr = 0; rr < 8; rr++){
      float4 o;
      o.x = fmaxf(acc[rr][0]+bb.x, 0.f);
      o.y = fmaxf(acc[rr][1]+bb.y, 0.f);
      o.z = fmaxf(acc[rr][2]+bb.z, 0.f);
      o.w = fmaxf(acc[rr][3]+bb.w, 0.f);
      *(float4*)(O1 + (tr*8+rr)*256 + 4*tc) = o;
    }
  }
  __syncthreads();
  #pragma unroll
  for (int rr = 0; rr < 8; rr++){ acc[rr][0]=acc[rr][1]=acc[rr][2]=acc[rr][3]=0.f; }
  gemm_f32(O1, W2, acc, tr, tc);
  {
    float4 bb = *(const float4*)(b2 + 4*tc);
    float ls0=0,ls1=0,ls2=0,ls3=0,lq0=0,lq1=0,lq2=0,lq3=0;
    #pragma unroll
    for (int rr = 0; rr < 8; rr++){
      float4 v;
      v.x = fmaxf(acc[rr][0]+bb.x, 0.f);
      v.y = fmaxf(acc[rr][1]+bb.y, 0.f);
      v.z = fmaxf(acc[rr][2]+bb.z, 0.f);
      v.w = fmaxf(acc[rr][3]+bb.w, 0.f);
      *(float4*)(h3 + ((size_t)(r0 + tr*8 + rr))*256 + 4*tc) = v;
      ls0+=v.x; lq0+=v.x*v.x; ls1+=v.y; lq1+=v.y*v.y;
      ls2+=v.z; lq2+=v.z*v.z; ls3+=v.w; lq3+=v.w*v.w;
    }
    atomicAdd(&red[4*tc+0], ls0); atomicAdd(&red[4*tc+1], ls1);
    atomicAdd(&red[4*tc+2], ls2); atomicAdd(&red[4*tc+3], ls3);
    atomicAdd(&red[256+4*tc+0], lq0); atomicAdd(&red[256+4*tc+1], lq1);
    atomicAdd(&red[256+4*tc+2], lq2); atomicAdd(&red[256+4*tc+3], lq3);
  }
  STATS_PUSH(stats3)
}

// ---------------- mlp4 (MFMA): [gather(bn3(h3)), bn2(h2)] -> [79200,768] -> h4 + stats ----------------
__global__ __launch_bounds__(256,2) void k_mlp4(
    const float* __restrict__ h3, const unsigned short* __restrict__ h2,
    const float* __restrict__ stats3, const float* __restrict__ g3, const float* __restrict__ be3,
    const float* __restrict__ stats2, const float* __restrict__ g2, const float* __restrict__ be2,
    const unsigned short* __restrict__ W1f, const float* __restrict__ b1,
    const unsigned short* __restrict__ W2f, const float* __restrict__ b2,
    unsigned short* __restrict__ h4, float* __restrict__ stats4){
  __shared__ unsigned short A[32*768];    // swizzled
  __shared__ unsigned short O1[32*256];   // swizzled
  __shared__ float a3[256], c3[256], a2[256], c2[256];
  __shared__ float red[512];
  int tid = threadIdx.x, w = tid >> 6, lane = tid & 63;
  int l15 = lane & 15, kg = lane >> 4;
  int r0 = blockIdx.x * 32;
  affine_prologue(stats3, (float)RN, g3, be3, a3, c3, tid);
  affine_prologue(stats2, (float)RE, g2, be2, a2, c2, tid);
  red[tid] = 0.f; red[tid + 256] = 0.f;
  __syncthreads();
  { // part A: cols 0..511 = gather(bn3(h3)): senders then receivers
    int cb = (lane & 31) * 8, half = lane >> 5;
    float4 a0 = *(const float4*)(a3+cb), a1 = *(const float4*)(a3+cb+4);
    float4 c0 = *(const float4*)(c3+cb), c1 = *(const float4*)(c3+cb+4);
    #pragma unroll
    for (int rr = 0; rr < 8; rr++){
      int rl = w*8+rr, rg = r0 + rl;
      int b = rg / Ee, e = rg - b*Ee;
      int i = e / 99, kk = e - i*99;
      int snd = kk + (kk >= i);
      int node = half ? i : snd;
      const float* sp = h3 + ((size_t)(b*Nn + node))*256 + cb;
      float4 v0 = *(const float4*)sp, v1 = *(const float4*)(sp+4);
      ushort8_t o;
      o[0]=f2bf(v0.x*a0.x+c0.x); o[1]=f2bf(v0.y*a0.y+c0.y);
      o[2]=f2bf(v0.z*a0.z+c0.z); o[3]=f2bf(v0.w*a0.w+c0.w);
      o[4]=f2bf(v1.x*a1.x+c1.x); o[5]=f2bf(v1.y*a1.y+c1.y);
      o[6]=f2bf(v1.z*a1.z+c1.z); o[7]=f2bf(v1.w*a1.w+c1.w);
      int byte = ((rl*768 + half*256 + cb)*2) ^ ((rl&7)<<4);
      *(ushort8_t*)((char*)A + byte) = o;
    }
  }
  { // part B: cols 512..767 = bn2(h2[row]) (skip connection)
    int cb = lane * 4;
    float4 av = *(const float4*)(a2+cb), cv = *(const float4*)(c2+cb);
    #pragma unroll
    for (int rr = 0; rr < 8; rr++){
      int rl = w*8+rr, rg = r0 + rl;
      ushort4_t hv = *(const ushort4_t*)(h2 + (size_t)rg*256 + cb);
      ushort4_t o;
      o[0]=f2bf(bf2f(hv[0])*av.x+cv.x);
      o[1]=f2bf(bf2f(hv[1])*av.y+cv.y);
      o[2]=f2bf(bf2f(hv[2])*av.z+cv.z);
      o[3]=f2bf(bf2f(hv[3])*av.w+cv.w);
      int byte = ((rl*768 + 512 + cb)*2) ^ ((rl&7)<<4);
      *(ushort4_t*)((char*)A + byte) = o;
    }
  }
  __syncthreads();
  f32x4 acc[2][4];
  zero_acc(acc);
  mfma_gemm<768>(A, W1f, acc, w, lane);
  { // bias+relu -> O1 (swizzled)
    #pragma unroll
    for (int cf = 0; cf < 4; cf++){
      int col = w*64 + cf*16 + l15;
      float bb = b1[col];
      #pragma unroll
      for (int rf = 0; rf < 2; rf++){
        #pragma unroll
        for (int r = 0; r < 4; r++){
          int row = rf*16 + kg*4 + r;
          float v = fmaxf(acc[rf][cf][r] + bb, 0.f);
          int byte = ((row*256 + col)*2) ^ ((row&7)<<4);
          *(unsigned short*)((char*)O1 + byte) = f2bf(v);
        }
      }
    }
  }
  __syncthreads();
  f32x4 acc2[2][4];
  zero_acc(acc2);
  mfma_gemm<256>(O1, W2f, acc2, w, lane);
  { // bias+relu -> h4 + stats
    #pragma unroll
    for (int cf = 0; cf < 4; cf++){
      int col = w*64 + cf*16 + l15;
      float bb = b2[col];
      float ls = 0.f, lq = 0.f;
      #pragma unroll
      for (int rf = 0; rf < 2; rf++){
        #pragma unroll
        for (int r = 0; r < 4; r++){
          int row = rf*16 + kg*4 + r;
          float v = fmaxf(acc2[rf][cf][r] + bb, 0.f);
          h4[(size_t)(r0 + row)*256 + col] = f2bf(v);
          ls += v; lq += v*v;
        }
      }
      atomicAdd(&red[col], ls);
      atomicAdd(&red[256+col], lq);
    }
  }
  STATS_PUSH(stats4)
}

// ---------------- out: bn4(h4) @ fc_w + fc_b -> [79200,4] f32 ----------------
__global__ __launch_bounds__(256,2) void k_out(
    const unsigned short* __restrict__ h4, const float* __restrict__ stats4,
    const float* __restrict__ g4, const float* __restrict__ be4,
    const float* __restrict__ fcw, const float* __restrict__ fcb,
    float* __restrict__ out){
  __shared__ unsigned short T[64*264];   // pad 256->264 to break bank alignment
  __shared__ float a4[256], c4[256], Wl[1024];
  int tid = threadIdx.x;
  affine_prologue(stats4, (float)RE, g4, be4, a4, c4, tid);
  #pragma unroll
  for (int j = 0; j < 4; j++){ int id = tid + j*256; Wl[id] = fcw[id]; }
  int r0 = blockIdx.x * 64;
  #pragma unroll
  for (int j = 0; j < 8; j++){
    int flat = tid + j*256;            // 2048 ushort8 chunks = 64 rows x 32 chunks
    int rl = flat >> 5, cs = (flat & 31) * 8;
    ushort8_t v = {0,0,0,0,0,0,0,0};
    if (r0 + rl < RE) v = *(const ushort8_t*)(h4 + (size_t)(r0+rl)*256 + cs);
    *(ushort8_t*)(&T[rl*264 + cs]) = v;
  }
  __syncthreads();
  int row = tid >> 2, o = tid & 3;
  if (r0 + row < RE){
    float acc = fcb[o];
    for (int k = 0; k < 256; k += 8){
      ushort8_t iv = *(const ushort8_t*)(&T[row*264 + k]);
      #pragma unroll
      for (int kk = 0; kk < 8; kk++){
        float v = bf2f(iv[kk]) * a4[k+kk] + c4[k+kk];
        acc += v * Wl[(k+kk)*4 + o];
      }
    }
    out[(size_t)(r0+row)*4 + o] = acc;
  }
}

extern "C" void kernel_launch(void* const* d_in, const int* in_sizes, int n_in,
                              void* d_out, int out_size, void* d_ws, size_t ws_size,
                              hipStream_t stream){
  const float* x    = (const float*)d_in[0];
  const float* m1w1 = (const float*)d_in[6];  const float* m1b1 = (const float*)d_in[7];
  const float* m1w2 = (const float*)d_in[8];  const float* m1b2 = (const float*)d_in[9];
  const float* m1g  = (const float*)d_in[10]; const float* m1be = (const float*)d_in[11];
  const float* m2w1 = (const float*)d_in[12]; const float* m2b1 = (const float*)d_in[13];
  const float* m2w2 = (const float*)d_in[14]; const float* m2b2 = (const float*)d_in[15];
  const float* m2g  = (const float*)d_in[16]; const float* m2be = (const float*)d_in[17];
  const float* m3w1 = (const float*)d_in[18]; const float* m3b1 = (const float*)d_in[19];
  const float* m3w2 = (const float*)d_in[20]; const float* m3b2 = (const float*)d_in[21];
  const float* m3g  = (const float*)d_in[22]; const float* m3be = (const float*)d_in[23];
  const float* m4w1 = (const float*)d_in[24]; const float* m4b1 = (const float*)d_in[25];
  const float* m4w2 = (const float*)d_in[26]; const float* m4b2 = (const float*)d_in[27];
  const float* m4g  = (const float*)d_in[28]; const float* m4be = (const float*)d_in[29];
  const float* fcw  = (const float*)d_in[30]; const float* fcb  = (const float*)d_in[31];

  // Workspace: h1/h3 f32, stats, h2/h4 bf16, fragment-packed bf16 weights (mlp2/mlp4)
  size_t need_bytes = (204800ull + 204800ull + 2048ull) * 4ull
                    + 2ull * (size_t)RE * 256ull * 2ull
                    + 458752ull * 2ull;
  if (ws_size < need_bytes) return;   // diagnosable clean failure instead of OOB crash

  float* ws = (float*)d_ws;
  float* h1 = ws;                        // 800*256 f32
  float* h3 = ws + 204800;               // 800*256 f32
  float* stats = ws + 409600;            // 4 stages x 512 f32 (sum|sumsq)
  unsigned short* h2 = (unsigned short*)(stats + 2048);   // 79200*256 bf16
  unsigned short* h4 = h2 + (size_t)RE * 256;             // 79200*256 bf16
  unsigned short* w2a = h4 + (size_t)RE * 256;            // 512*256 frag bf16
  unsigned short* w2b = w2a + 512*256;                    // 256*256
  unsigned short* w4a = w2b + 256*256;                    // 768*256
  unsigned short* w4b = w4a + 768*256;                    // 256*256

  hipMemsetAsync(stats, 0, 2048 * sizeof(float), stream);

  k_wprep<<<(16*16*64)/256, 256, 0, stream>>>(m2w1, w2a, 16);
  k_wprep<<<( 8*16*64)/256, 256, 0, stream>>>(m2w2, w2b, 8);
  k_wprep<<<(24*16*64)/256, 256, 0, stream>>>(m4w1, w4a, 24);
  k_wprep<<<( 8*16*64)/256, 256, 0, stream>>>(m4w2, w4b, 8);

  k_mlp1<<<RN/32, 256, 0, stream>>>(x, m1w1, m1b1, m1w2, m1b2, h1, stats);
  k_mlp2<<<RE/32, 256, 0, stream>>>(h1, stats, m1g, m1be,
                                    w2a, m2b1, w2b, m2b2, h2, stats + 512);
  k_mlp3<<<RN/32, 256, 0, stream>>>(h2, stats + 512, m2g, m2be,
                                    m3w1, m3b1, m3w2, m3b2, h3, stats + 1024);
  k_mlp4<<<RE/32, 256, 0, stream>>>(h3, h2, stats + 1024, m3g, m3be,
                                    stats + 512, m2g, m2be,
                                    w4a, m4b1, w4b, m4b2, h4, stats + 1536);
  k_out<<<(RE+63)/64, 256, 0, stream>>>(h4, stats + 1536, m4g, m4be,
                                        fcw, fcb, (float*)d_out);
}

// Round 6
// 478.581 us; speedup vs baseline: 2.6095x; 1.0410x over previous
//
#include <hip/hip_runtime.h>
#include <hip/hip_bf16.h>

#define Nn 100
#define Bb 8
#define Hh 256
#define Ee 9900
#define RE 79200   // Bb*Ee
#define RN 800     // Bb*Nn
#define BN_EPS 1e-5f

typedef __attribute__((ext_vector_type(8))) unsigned short ushort8_t;
typedef __attribute__((ext_vector_type(4))) unsigned short ushort4_t;
typedef __attribute__((ext_vector_type(8))) short bf16x8;   // MFMA A/B frag (4 VGPRs)
typedef __attribute__((ext_vector_type(4))) float f32x4;    // MFMA C/D frag

__device__ __forceinline__ float bf2f(unsigned short u){
  return __uint_as_float(((unsigned)u) << 16);
}
__device__ __forceinline__ unsigned short f2bf(float f){
  unsigned u = __float_as_uint(f);
  return (unsigned short)((u + 0x7fffu + ((u >> 16) & 1u)) >> 16);
}

// BN affine via LDS (for mlp3 which is not LDS-constrained)
__device__ __forceinline__ void affine_prologue(const float* __restrict__ stats,
    float cnt, const float* __restrict__ g, const float* __restrict__ beta,
    float* a, float* c, int tid){
  if (tid < 256){
    float inv = 1.0f / cnt;
    float mu  = stats[tid] * inv;
    float var = fmaxf(stats[256 + tid] * inv - mu * mu, 0.f);
    float aa  = g[tid] * rsqrtf(var + BN_EPS);
    a[tid] = aa;
    c[tid] = beta[tid] - mu * aa;
  }
}

// BN affine in registers (4 cols starting at cb) — frees LDS in the MFMA kernels
__device__ __forceinline__ void affine_reg(const float* __restrict__ stats,
    float cnt, const float* __restrict__ g, const float* __restrict__ be,
    int cb, float4& av, float4& cv){
  float4 s = *(const float4*)(stats + cb);
  float4 q = *(const float4*)(stats + 256 + cb);
  float4 gg = *(const float4*)(g + cb);
  float4 bb = *(const float4*)(be + cb);
  float inv = 1.0f / cnt;
  float mx = s.x*inv, my = s.y*inv, mz = s.z*inv, mw = s.w*inv;
  av.x = gg.x * rsqrtf(fmaxf(q.x*inv - mx*mx, 0.f) + BN_EPS); cv.x = bb.x - mx*av.x;
  av.y = gg.y * rsqrtf(fmaxf(q.y*inv - my*my, 0.f) + BN_EPS); cv.y = bb.y - my*av.y;
  av.z = gg.z * rsqrtf(fmaxf(q.z*inv - mz*mz, 0.f) + BN_EPS); cv.z = bb.z - mz*av.z;
  av.w = gg.w * rsqrtf(fmaxf(q.w*inv - mw*mw, 0.f) + BN_EPS); cv.w = bb.w - mw*av.w;
}

// acc[8][4] += IN(32x256 f32 LDS) @ W(256x256 f32 global). thread: tr=tid>>6, tc=tid&63
__device__ __forceinline__ void gemm_f32(const float* IN, const float* __restrict__ W,
                                         float acc[8][4], int tr, int tc){
  for (int k = 0; k < 256; k += 4){
    float4 w0 = *(const float4*)(W + (size_t)(k+0)*256 + 4*tc);
    float4 w1 = *(const float4*)(W + (size_t)(k+1)*256 + 4*tc);
    float4 w2 = *(const float4*)(W + (size_t)(k+2)*256 + 4*tc);
    float4 w3 = *(const float4*)(W + (size_t)(k+3)*256 + 4*tc);
    #pragma unroll
    for (int rr = 0; rr < 8; rr++){
      float4 iv = *(const float4*)(IN + (tr*8+rr)*256 + k);
      acc[rr][0] += iv.x*w0.x + iv.y*w1.x + iv.z*w2.x + iv.w*w3.x;
      acc[rr][1] += iv.x*w0.y + iv.y*w1.y + iv.z*w2.y + iv.w*w3.y;
      acc[rr][2] += iv.x*w0.z + iv.y*w1.z + iv.z*w2.z + iv.w*w3.z;
      acc[rr][3] += iv.x*w0.w + iv.y*w1.w + iv.z*w2.w + iv.w*w3.w;
    }
  }
}

// MFMA GEMM: A = LDS [32][KW] bf16 row-major, XOR-swizzled (byte ^= (row&7)<<4).
// B = fragment-packed bf16 weights (see k_wprep). Wave w owns output cols [w*64, w*64+64).
template<int KW>
__device__ __forceinline__ void mfma_gemm(const unsigned short* Alds,
    const unsigned short* __restrict__ Bf, f32x4 acc[2][4], int w, int lane){
  const int l15 = lane & 15, kg = lane >> 4;
  for (int ks = 0; ks < KW/32; ks++){
    int byte0 = ((l15*KW      + ks*32 + kg*8) * 2) ^ ((l15 & 7) << 4);
    int byte1 = (((16+l15)*KW + ks*32 + kg*8) * 2) ^ ((l15 & 7) << 4);
    bf16x8 a0 = *(const bf16x8*)((const char*)Alds + byte0);
    bf16x8 a1 = *(const bf16x8*)((const char*)Alds + byte1);
    const unsigned short* bp = Bf + ((size_t)(ks*16 + w*4)*64 + lane)*8;
    #pragma unroll
    for (int cf = 0; cf < 4; cf++){
      bf16x8 b = *(const bf16x8*)(bp + cf*64*8);
      acc[0][cf] = __builtin_amdgcn_mfma_f32_16x16x32_bf16(a0, b, acc[0][cf], 0,0,0);
      acc[1][cf] = __builtin_amdgcn_mfma_f32_16x16x32_bf16(a1, b, acc[1][cf], 0,0,0);
    }
  }
}

__device__ __forceinline__ void zero_acc(f32x4 acc[2][4]){
  #pragma unroll
  for (int i = 0; i < 2; i++)
    #pragma unroll
    for (int j = 0; j < 4; j++){
      f32x4 z = {0.f, 0.f, 0.f, 0.f};
      acc[i][j] = z;
    }
}

// stats push helper: red[512] LDS partials -> global stats (256 threads: 2 entries each)
#define STATS_PUSH(statsp)                                   \
  __syncthreads();                                           \
  atomicAdd(&(statsp)[tid], red[tid]);                       \
  atomicAdd(&(statsp)[tid + 256], red[tid + 256]);

// ---------------- weight prep: W f32 [ktiles*32, 256] -> B-fragment bf16 layout ----------------
__global__ void k_wprep(const float* __restrict__ W, unsigned short* __restrict__ out,
                        int ktiles){
  int id = blockIdx.x * 256 + threadIdx.x;
  int total = ktiles * 16 * 64;
  if (id >= total) return;
  int lane = id & 63, tile = id >> 6;
  int tc = tile & 15, tk = tile >> 4;
  int kbase = tk*32 + (lane>>4)*8, col = tc*16 + (lane&15);
  ushort8_t o;
  #pragma unroll
  for (int j = 0; j < 8; j++) o[j] = f2bf(W[(size_t)(kbase+j)*256 + col]);
  *(ushort8_t*)(out + (size_t)id*8) = o;
}

// ---------------- mlp1: [800,256] -> h1 (f32) + stats ----------------
__global__ __launch_bounds__(256,2) void k_mlp1(
    const float* __restrict__ x,
    const float* __restrict__ W1, const float* __restrict__ b1,
    const float* __restrict__ W2, const float* __restrict__ b2,
    float* __restrict__ h1, float* __restrict__ stats){
  __shared__ float IN[32*256];
  __shared__ float O1[32*256];
  __shared__ float red[512];
  int tid = threadIdx.x, tr = tid >> 6, tc = tid & 63;
  int r0 = blockIdx.x * 32;
  #pragma unroll
  for (int j = 0; j < 8; j++){
    int idx = tid*4 + j*1024;
    *(float4*)(IN + idx) = *(const float4*)(x + (size_t)r0*256 + idx);
  }
  red[tid] = 0.f; red[tid + 256] = 0.f;
  __syncthreads();
  float acc[8][4];
  #pragma unroll
  for (int rr = 0; rr < 8; rr++){ acc[rr][0]=acc[rr][1]=acc[rr][2]=acc[rr][3]=0.f; }
  gemm_f32(IN, W1, acc, tr, tc);
  {
    float4 bb = *(const float4*)(b1 + 4*tc);
    #pragma unroll
    for (int rr = 0; rr < 8; rr++){
      float4 o;
      o.x = fmaxf(acc[rr][0]+bb.x, 0.f);
      o.y = fmaxf(acc[rr][1]+bb.y, 0.f);
      o.z = fmaxf(acc[rr][2]+bb.z, 0.f);
      o.w = fmaxf(acc[rr][3]+bb.w, 0.f);
      *(float4*)(O1 + (tr*8+rr)*256 + 4*tc) = o;
    }
  }
  __syncthreads();
  #pragma unroll
  for (int rr = 0; rr < 8; rr++){ acc[rr][0]=acc[rr][1]=acc[rr][2]=acc[rr][3]=0.f; }
  gemm_f32(O1, W2, acc, tr, tc);
  {
    float4 bb = *(const float4*)(b2 + 4*tc);
    float ls0=0,ls1=0,ls2=0,ls3=0,lq0=0,lq1=0,lq2=0,lq3=0;
    #pragma unroll
    for (int rr = 0; rr < 8; rr++){
      float4 v;
      v.x = fmaxf(acc[rr][0]+bb.x, 0.f);
      v.y = fmaxf(acc[rr][1]+bb.y, 0.f);
      v.z = fmaxf(acc[rr][2]+bb.z, 0.f);
      v.w = fmaxf(acc[rr][3]+bb.w, 0.f);
      *(float4*)(h1 + ((size_t)(r0 + tr*8 + rr))*256 + 4*tc) = v;
      ls0+=v.x; lq0+=v.x*v.x; ls1+=v.y; lq1+=v.y*v.y;
      ls2+=v.z; lq2+=v.z*v.z; ls3+=v.w; lq3+=v.w*v.w;
    }
    atomicAdd(&red[4*tc+0], ls0); atomicAdd(&red[4*tc+1], ls1);
    atomicAdd(&red[4*tc+2], ls2); atomicAdd(&red[4*tc+3], ls3);
    atomicAdd(&red[256+4*tc+0], lq0); atomicAdd(&red[256+4*tc+1], lq1);
    atomicAdd(&red[256+4*tc+2], lq2); atomicAdd(&red[256+4*tc+3], lq3);
  }
  STATS_PUSH(stats)
}

// ---------------- mlp2 (MFMA, slim LDS): gather(h1)+bn1 -> [79200,512] -> h2 + stats ----------------
__global__ __launch_bounds__(256,4) void k_mlp2(
    const float* __restrict__ h1, const float* __restrict__ stats1,
    const float* __restrict__ g1, const float* __restrict__ be1,
    const unsigned short* __restrict__ W1f, const float* __restrict__ b1,
    const unsigned short* __restrict__ W2f, const float* __restrict__ b2,
    unsigned short* __restrict__ h2, float* __restrict__ stats2){
  __shared__ unsigned short A[32*512];    // swizzled; O1 aliases into this after GEMM1
  __shared__ float red[512];
  int tid = threadIdx.x, w = tid >> 6, lane = tid & 63;
  int l15 = lane & 15, kg = lane >> 4;
  int r0 = blockIdx.x * 32;
  red[tid] = 0.f; red[tid + 256] = 0.f;
  { // gather + bn1 (register affine) -> A (swizzled bf16)
    int cb = (lane & 31) * 8, half = lane >> 5;
    float4 a0, c0, a1, c1;
    affine_reg(stats1, (float)RN, g1, be1, cb,     a0, c0);
    affine_reg(stats1, (float)RN, g1, be1, cb + 4, a1, c1);
    #pragma unroll
    for (int rr = 0; rr < 8; rr++){
      int rl = w*8+rr, rg = r0 + rl;
      int b = rg / Ee, e = rg - b*Ee;
      int i = e / 99, kk = e - i*99;
      int snd = kk + (kk >= i);
      int node = half ? i : snd;
      const float* sp = h1 + ((size_t)(b*Nn + node))*256 + cb;
      float4 v0 = *(const float4*)sp, v1 = *(const float4*)(sp+4);
      ushort8_t o;
      o[0]=f2bf(v0.x*a0.x+c0.x); o[1]=f2bf(v0.y*a0.y+c0.y);
      o[2]=f2bf(v0.z*a0.z+c0.z); o[3]=f2bf(v0.w*a0.w+c0.w);
      o[4]=f2bf(v1.x*a1.x+c1.x); o[5]=f2bf(v1.y*a1.y+c1.y);
      o[6]=f2bf(v1.z*a1.z+c1.z); o[7]=f2bf(v1.w*a1.w+c1.w);
      int byte = ((rl*512 + half*256 + cb)*2) ^ ((rl&7)<<4);
      *(ushort8_t*)((char*)A + byte) = o;
    }
  }
  __syncthreads();
  f32x4 acc[2][4];
  zero_acc(acc);
  mfma_gemm<512>(A, W1f, acc, w, lane);
  __syncthreads();               // all waves done reading A before O1 overwrites it
  unsigned short* O1 = A;        // alias: [32][256] swizzled
  { // bias+relu -> O1
    #pragma unroll
    for (int cf = 0; cf < 4; cf++){
      int col = w*64 + cf*16 + l15;
      float bb = b1[col];
      #pragma unroll
      for (int rf = 0; rf < 2; rf++){
        #pragma unroll
        for (int r = 0; r < 4; r++){
          int row = rf*16 + kg*4 + r;
          float v = fmaxf(acc[rf][cf][r] + bb, 0.f);
          int byte = ((row*256 + col)*2) ^ ((row&7)<<4);
          *(unsigned short*)((char*)O1 + byte) = f2bf(v);
        }
      }
    }
  }
  __syncthreads();
  f32x4 acc2[2][4];
  zero_acc(acc2);
  mfma_gemm<256>(O1, W2f, acc2, w, lane);
  { // bias+relu -> h2 + stats
    #pragma unroll
    for (int cf = 0; cf < 4; cf++){
      int col = w*64 + cf*16 + l15;
      float bb = b2[col];
      float ls = 0.f, lq = 0.f;
      #pragma unroll
      for (int rf = 0; rf < 2; rf++){
        #pragma unroll
        for (int r = 0; r < 4; r++){
          int row = rf*16 + kg*4 + r;
          float v = fmaxf(acc2[rf][cf][r] + bb, 0.f);
          h2[(size_t)(r0 + row)*256 + col] = f2bf(v);
          ls += v; lq += v*v;
        }
      }
      atomicAdd(&red[col], ls);
      atomicAdd(&red[256+col], lq);
    }
  }
  STATS_PUSH(stats2)
}

// ---------------- e2n: column-parallel incoming-edge sum, 800 blocks ----------------
__global__ __launch_bounds__(256,4) void k_e2n(
    const unsigned short* __restrict__ h2, float* __restrict__ h3in){
  int m = blockIdx.x;                 // node-row 0..799
  int b = m / Nn, i = m - b*Nn;
  int c = threadIdx.x;                // column 0..255
  const unsigned short* base = h2 + ((size_t)(b*Ee + i*99))*256 + c;
  float s = 0.f;
  #pragma unroll 4
  for (int j = 0; j < 99; j++) s += bf2f(base[(size_t)j*256]);
  h3in[(size_t)m*256 + c] = s;        // raw sum; bn2 affine + /N applied in k_mlp3
}

// ---------------- mlp3: bn2-affine(e2n sums)/N -> [800,256] -> h3 (f32) + stats ----------------
__global__ __launch_bounds__(256,2) void k_mlp3(
    const float* __restrict__ h3in, const float* __restrict__ stats2,
    const float* __restrict__ g2, const float* __restrict__ be2,
    const float* __restrict__ W1, const float* __restrict__ b1,
    const float* __restrict__ W2, const float* __restrict__ b2,
    float* __restrict__ h3, float* __restrict__ stats3){
  __shared__ float IN[32*256];
  __shared__ float O1[32*256];
  __shared__ float red[512];
  __shared__ float ap[256], cp[256];
  int tid = threadIdx.x, tr = tid >> 6, lane = tid & 63, tc = lane;
  int r0 = blockIdx.x * 32;
  affine_prologue(stats2, (float)RE, g2, be2, ap, cp, tid);
  red[tid] = 0.f; red[tid + 256] = 0.f;
  __syncthreads();
  {
    int cb = lane * 4;
    float4 av = *(const float4*)(ap+cb), cv = *(const float4*)(cp+cb);
    #pragma unroll
    for (int rr = 0; rr < 8; rr++){
      int m = r0 + tr*8 + rr;
      float4 s = *(const float4*)(h3in + (size_t)m*256 + cb);
      float4 o;
      o.x = (s.x*av.x + 99.f*cv.x) * 0.01f;
      o.y = (s.y*av.y + 99.f*cv.y) * 0.01f;
      o.z = (s.z*av.z + 99.f*cv.z) * 0.01f;
      o.w = (s.w*av.w + 99.f*cv.w) * 0.01f;
      *(float4*)(IN + (tr*8+rr)*256 + cb) = o;
    }
  }
  __syncthreads();
  float acc[8][4];
  #pragma unroll
  for (int rr = 0; rr < 8; rr++){ acc[rr][0]=acc[rr][1]=acc[rr][2]=acc[rr][3]=0.f; }
  gemm_f32(IN, W1, acc, tr, tc);
  {
    float4 bb = *(const float4*)(b1 + 4*tc);
    #pragma unroll
    for (int rr = 0; rr < 8; rr++){
      float4 o;
      o.x = fmaxf(acc[rr][0]+bb.x, 0.f);
      o.y = fmaxf(acc[rr][1]+bb.y, 0.f);
      o.z = fmaxf(acc[rr][2]+bb.z, 0.f);
      o.w = fmaxf(acc[rr][3]+bb.w, 0.f);
      *(float4*)(O1 + (tr*8+rr)*256 + 4*tc) = o;
    }
  }
  __syncthreads();
  #pragma unroll
  for (int rr = 0; rr < 8; rr++){ acc[rr][0]=acc[rr][1]=acc[rr][2]=acc[rr][3]=0.f; }
  gemm_f32(O1, W2, acc, tr, tc);
  {
    float4 bb = *(const float4*)(b2 + 4*tc);
    float ls0=0,ls1=0,ls2=0,ls3=0,lq0=0,lq1=0,lq2=0,lq3=0;
    #pragma unroll
    for (int rr = 0; rr < 8; rr++){
      float4 v;
      v.x = fmaxf(acc[rr][0]+bb.x, 0.f);
      v.y = fmaxf(acc[rr][1]+bb.y, 0.f);
      v.z = fmaxf(acc[rr][2]+bb.z, 0.f);
      v.w = fmaxf(acc[rr][3]+bb.w, 0.f);
      *(float4*)(h3 + ((size_t)(r0 + tr*8 + rr))*256 + 4*tc) = v;
      ls0+=v.x; lq0+=v.x*v.x; ls1+=v.y; lq1+=v.y*v.y;
      ls2+=v.z; lq2+=v.z*v.z; ls3+=v.w; lq3+=v.w*v.w;
    }
    atomicAdd(&red[4*tc+0], ls0); atomicAdd(&red[4*tc+1], ls1);
    atomicAdd(&red[4*tc+2], ls2); atomicAdd(&red[4*tc+3], ls3);
    atomicAdd(&red[256+4*tc+0], lq0); atomicAdd(&red[256+4*tc+1], lq1);
    atomicAdd(&red[256+4*tc+2], lq2); atomicAdd(&red[256+4*tc+3], lq3);
  }
  STATS_PUSH(stats3)
}

// ---------------- mlp4 (MFMA, slim LDS): [gather(bn3(h3)), bn2(h2)] -> [79200,768] -> h4 ----------------
__global__ __launch_bounds__(256,3) void k_mlp4(
    const float* __restrict__ h3, const unsigned short* __restrict__ h2,
    const float* __restrict__ stats3, const float* __restrict__ g3, const float* __restrict__ be3,
    const float* __restrict__ stats2, const float* __restrict__ g2, const float* __restrict__ be2,
    const unsigned short* __restrict__ W1f, const float* __restrict__ b1,
    const unsigned short* __restrict__ W2f, const float* __restrict__ b2,
    unsigned short* __restrict__ h4, float* __restrict__ stats4){
  __shared__ unsigned short A[32*768];    // swizzled; O1 aliases into this after GEMM1
  __shared__ float red[512];
  int tid = threadIdx.x, w = tid >> 6, lane = tid & 63;
  int l15 = lane & 15, kg = lane >> 4;
  int r0 = blockIdx.x * 32;
  red[tid] = 0.f; red[tid + 256] = 0.f;
  { // part A: cols 0..511 = gather(bn3(h3)) with register affine
    int cb = (lane & 31) * 8, half = lane >> 5;
    float4 a0, c0, a1, c1;
    affine_reg(stats3, (float)RN, g3, be3, cb,     a0, c0);
    affine_reg(stats3, (float)RN, g3, be3, cb + 4, a1, c1);
    #pragma unroll
    for (int rr = 0; rr < 8; rr++){
      int rl = w*8+rr, rg = r0 + rl;
      int b = rg / Ee, e = rg - b*Ee;
      int i = e / 99, kk = e - i*99;
      int snd = kk + (kk >= i);
      int node = half ? i : snd;
      const float* sp = h3 + ((size_t)(b*Nn + node))*256 + cb;
      float4 v0 = *(const float4*)sp, v1 = *(const float4*)(sp+4);
      ushort8_t o;
      o[0]=f2bf(v0.x*a0.x+c0.x); o[1]=f2bf(v0.y*a0.y+c0.y);
      o[2]=f2bf(v0.z*a0.z+c0.z); o[3]=f2bf(v0.w*a0.w+c0.w);
      o[4]=f2bf(v1.x*a1.x+c1.x); o[5]=f2bf(v1.y*a1.y+c1.y);
      o[6]=f2bf(v1.z*a1.z+c1.z); o[7]=f2bf(v1.w*a1.w+c1.w);
      int byte = ((rl*768 + half*256 + cb)*2) ^ ((rl&7)<<4);
      *(ushort8_t*)((char*)A + byte) = o;
    }
  }
  { // part B: cols 512..767 = bn2(h2[row]) (skip connection), register affine
    int cb = lane * 4;
    float4 av, cv;
    affine_reg(stats2, (float)RE, g2, be2, cb, av, cv);
    #pragma unroll
    for (int rr = 0; rr < 8; rr++){
      int rl = w*8+rr, rg = r0 + rl;
      ushort4_t hv = *(const ushort4_t*)(h2 + (size_t)rg*256 + cb);
      ushort4_t o;
      o[0]=f2bf(bf2f(hv[0])*av.x+cv.x);
      o[1]=f2bf(bf2f(hv[1])*av.y+cv.y);
      o[2]=f2bf(bf2f(hv[2])*av.z+cv.z);
      o[3]=f2bf(bf2f(hv[3])*av.w+cv.w);
      int byte = ((rl*768 + 512 + cb)*2) ^ ((rl&7)<<4);
      *(ushort4_t*)((char*)A + byte) = o;
    }
  }
  __syncthreads();
  f32x4 acc[2][4];
  zero_acc(acc);
  mfma_gemm<768>(A, W1f, acc, w, lane);
  __syncthreads();               // all waves done reading A before O1 overwrites it
  unsigned short* O1 = A;        // alias: [32][256] swizzled
  { // bias+relu -> O1
    #pragma unroll
    for (int cf = 0; cf < 4; cf++){
      int col = w*64 + cf*16 + l15;
      float bb = b1[col];
      #pragma unroll
      for (int rf = 0; rf < 2; rf++){
        #pragma unroll
        for (int r = 0; r < 4; r++){
          int row = rf*16 + kg*4 + r;
          float v = fmaxf(acc[rf][cf][r] + bb, 0.f);
          int byte = ((row*256 + col)*2) ^ ((row&7)<<4);
          *(unsigned short*)((char*)O1 + byte) = f2bf(v);
        }
      }
    }
  }
  __syncthreads();
  f32x4 acc2[2][4];
  zero_acc(acc2);
  mfma_gemm<256>(O1, W2f, acc2, w, lane);
  { // bias+relu -> h4 + stats
    #pragma unroll
    for (int cf = 0; cf < 4; cf++){
      int col = w*64 + cf*16 + l15;
      float bb = b2[col];
      float ls = 0.f, lq = 0.f;
      #pragma unroll
      for (int rf = 0; rf < 2; rf++){
        #pragma unroll
        for (int r = 0; r < 4; r++){
          int row = rf*16 + kg*4 + r;
          float v = fmaxf(acc2[rf][cf][r] + bb, 0.f);
          h4[(size_t)(r0 + row)*256 + col] = f2bf(v);
          ls += v; lq += v*v;
        }
      }
      atomicAdd(&red[col], ls);
      atomicAdd(&red[256+col], lq);
    }
  }
  STATS_PUSH(stats4)
}

// ---------------- out: bn4(h4) @ fc_w + fc_b -> [79200,4] f32 ----------------
__global__ __launch_bounds__(256,2) void k_out(
    const unsigned short* __restrict__ h4, const float* __restrict__ stats4,
    const float* __restrict__ g4, const float* __restrict__ be4,
    const float* __restrict__ fcw, const float* __restrict__ fcb,
    float* __restrict__ out){
  __shared__ unsigned short T[64*264];   // pad 256->264 to break bank alignment
  __shared__ float a4[256], c4[256], Wl[1024];
  int tid = threadIdx.x;
  affine_prologue(stats4, (float)RE, g4, be4, a4, c4, tid);
  #pragma unroll
  for (int j = 0; j < 4; j++){ int id = tid + j*256; Wl[id] = fcw[id]; }
  int r0 = blockIdx.x * 64;
  #pragma unroll
  for (int j = 0; j < 8; j++){
    int flat = tid + j*256;
    int rl = flat >> 5, cs = (flat & 31) * 8;
    ushort8_t v = {0,0,0,0,0,0,0,0};
    if (r0 + rl < RE) v = *(const ushort8_t*)(h4 + (size_t)(r0+rl)*256 + cs);
    *(ushort8_t*)(&T[rl*264 + cs]) = v;
  }
  __syncthreads();
  int row = tid >> 2, o = tid & 3;
  if (r0 + row < RE){
    float acc = fcb[o];
    for (int k = 0; k < 256; k += 8){
      ushort8_t iv = *(const ushort8_t*)(&T[row*264 + k]);
      #pragma unroll
      for (int kk = 0; kk < 8; kk++){
        float v = bf2f(iv[kk]) * a4[k+kk] + c4[k+kk];
        acc += v * Wl[(k+kk)*4 + o];
      }
    }
    out[(size_t)(r0+row)*4 + o] = acc;
  }
}

extern "C" void kernel_launch(void* const* d_in, const int* in_sizes, int n_in,
                              void* d_out, int out_size, void* d_ws, size_t ws_size,
                              hipStream_t stream){
  const float* x    = (const float*)d_in[0];
  const float* m1w1 = (const float*)d_in[6];  const float* m1b1 = (const float*)d_in[7];
  const float* m1w2 = (const float*)d_in[8];  const float* m1b2 = (const float*)d_in[9];
  const float* m1g  = (const float*)d_in[10]; const float* m1be = (const float*)d_in[11];
  const float* m2w1 = (const float*)d_in[12]; const float* m2b1 = (const float*)d_in[13];
  const float* m2w2 = (const float*)d_in[14]; const float* m2b2 = (const float*)d_in[15];
  const float* m2g  = (const float*)d_in[16]; const float* m2be = (const float*)d_in[17];
  const float* m3w1 = (const float*)d_in[18]; const float* m3b1 = (const float*)d_in[19];
  const float* m3w2 = (const float*)d_in[20]; const float* m3b2 = (const float*)d_in[21];
  const float* m3g  = (const float*)d_in[22]; const float* m3be = (const float*)d_in[23];
  const float* m4w1 = (const float*)d_in[24]; const float* m4b1 = (const float*)d_in[25];
  const float* m4w2 = (const float*)d_in[26]; const float* m4b2 = (const float*)d_in[27];
  const float* m4g  = (const float*)d_in[28]; const float* m4be = (const float*)d_in[29];
  const float* fcw  = (const float*)d_in[30]; const float* fcb  = (const float*)d_in[31];

  // Workspace: h1/h3/h3in f32, stats, h2/h4 bf16, fragment-packed bf16 weights
  size_t need_bytes = (204800ull*3 + 2048ull) * 4ull
                    + 2ull * (size_t)RE * 256ull * 2ull
                    + 458752ull * 2ull;
  if (ws_size < need_bytes) return;

  float* ws = (float*)d_ws;
  float* h1   = ws;                      // 800*256 f32
  float* h3   = ws + 204800;             // 800*256 f32
  float* stats= ws + 409600;             // 4 stages x 512 f32 (sum|sumsq)
  float* h3in = ws + 411648;             // 800*256 f32 (e2n raw sums)
  unsigned short* h2 = (unsigned short*)(ws + 616448);    // 79200*256 bf16
  unsigned short* h4 = h2 + (size_t)RE * 256;             // 79200*256 bf16
  unsigned short* w2a = h4 + (size_t)RE * 256;            // 512*256 frag bf16
  unsigned short* w2b = w2a + 512*256;                    // 256*256
  unsigned short* w4a = w2b + 256*256;                    // 768*256
  unsigned short* w4b = w4a + 768*256;                    // 256*256

  hipMemsetAsync(stats, 0, 2048 * sizeof(float), stream);

  k_wprep<<<(16*16*64)/256, 256, 0, stream>>>(m2w1, w2a, 16);
  k_wprep<<<( 8*16*64)/256, 256, 0, stream>>>(m2w2, w2b, 8);
  k_wprep<<<(24*16*64)/256, 256, 0, stream>>>(m4w1, w4a, 24);
  k_wprep<<<( 8*16*64)/256, 256, 0, stream>>>(m4w2, w4b, 8);

  k_mlp1<<<RN/32, 256, 0, stream>>>(x, m1w1, m1b1, m1w2, m1b2, h1, stats);
  k_mlp2<<<RE/32, 256, 0, stream>>>(h1, stats, m1g, m1be,
                                    w2a, m2b1, w2b, m2b2, h2, stats + 512);
  k_e2n<<<RN, 256, 0, stream>>>(h2, h3in);
  k_mlp3<<<RN/32, 256, 0, stream>>>(h3in, stats + 512, m2g, m2be,
                                    m3w1, m3b1, m3w2, m3b2, h3, stats + 1024);
  k_mlp4<<<RE/32, 256, 0, stream>>>(h3, h2, stats + 1024, m3g, m3be,
                                    stats + 512, m2g, m2be,
                                    w4a, m4b1, w4b, m4b2, h4, stats + 1536);
  k_out<<<(RE+63)/64, 256, 0, stream>>>(h4, stats + 1536, m4g, m4be,
                                        fcw, fcb, (float*)d_out);
}